// Round 8
// baseline (283.999 us; speedup 1.0000x reference)
//
#include <hip/hip_runtime.h>
#include <math.h>

#define N_RES 8192
#define N_IN  128
#define BATCH 16
#define LEAK  0.9f

#define NBK   256      // pass-1 buckets (row>>5), 32 rows each
#define CAP1B 28672    // per-bucket capacity (avg 26.6K, +12 sigma)
#define CHUNK 4096     // entries per block chunk
#define SB2   (CAP1B / CHUNK)   // 7 chunks per bucket

// ws layout (bytes):
//   srcT     @ 0      : [8320][16] f32 transposed state|x  (532,480)
//   bcur     @ 1 MiB  : int[256]
//   partials @ 2 MiB  : [NBK][SB2][32][16] f32             (3,670,016)
//   e1       @ 8 MiB  : uint2[NBK][CAP1B]                  (58,720,256)
#define OFF_SRCT 0
#define OFF_BCUR (1u << 20)
#define OFF_PART (2u << 20)
#define OFF_E1   (8u << 20)
#define REQ_A    ((size_t)OFF_E1 + (size_t)NBK * CAP1B * 8)   // 64 MiB

// ---------------------------------------------------------------------------
__global__ __launch_bounds__(256) void transpose_kernel(
    const float* __restrict__ state,  // [BATCH][N_RES]
    const float* __restrict__ x,      // [BATCH][N_IN]
    float* __restrict__ srcT) {       // [8320][BATCH]
  int tid = blockIdx.x * 256 + threadIdx.x;
  if (tid < N_RES * BATCH) {
    int b = tid >> 13;
    int r = tid & (N_RES - 1);
    srcT[r * BATCH + b] = state[tid];
  }
  if (tid < N_IN * BATCH) {
    int b = tid >> 7;
    int c = tid & (N_IN - 1);
    srcT[(N_RES + c) * BATCH + b] = x[tid];
  }
}

// ---------------------------------------------------------------------------
// Pass 1: bin by row>>5 (256 buckets). LDS reorder -> coalesced bin writes.
// Prefix scan over the 256-bin histogram is a parallel wave-shuffle scan
// (was: serial loop on thread 0 under a barrier).
__global__ __launch_bounds__(256) void pass1_bin(
    const float* __restrict__ vals,
    const int* __restrict__ rows,
    const int* __restrict__ cols,
    int nnz, int col_off,
    uint2* __restrict__ e1,          // [NBK][CAP1B]
    int* __restrict__ bcur) {        // [NBK]
  __shared__ int hist[NBK];
  __shared__ int lbase[NBK];
  __shared__ int gbase[NBK];
  __shared__ int wsum[4];
  __shared__ uint2 stg[CHUNK];          // 32 KB
  __shared__ unsigned char binof[CHUNK];
  int tid = threadIdx.x;
  hist[tid] = 0;
  __syncthreads();

  int base = blockIdx.x * CHUNK;
  int n = nnz - base;
  if (n > CHUNK) n = CHUNK;

  uint2 ent[16];
  int bb[16], lp[16];
#pragma unroll
  for (int e = 0; e < 16; ++e) {
    int i = e * 256 + tid;
    bb[e] = -1;
    if (i < n) {
      int r = rows[base + i];
      int c = cols[base + i] + col_off;
      float v = vals[base + i];
      bb[e] = r >> 5;
      ent[e] = make_uint2(__float_as_uint(v),
                          ((unsigned)(r & 31) << 14) | (unsigned)c);
      lp[e] = atomicAdd(&hist[bb[e]], 1);
    }
  }
  __syncthreads();
  // Parallel exclusive scan of hist[256].
  int h = hist[tid];
  int v = h;
#pragma unroll
  for (int d = 1; d < 64; d <<= 1) {
    int t = __shfl_up(v, d);
    if ((tid & 63) >= d) v += t;
  }
  if ((tid & 63) == 63) wsum[tid >> 6] = v;
  __syncthreads();
  int off = 0;
#pragma unroll
  for (int w = 0; w < 4; ++w)
    if (w < (tid >> 6)) off += wsum[w];
  lbase[tid] = off + v - h;             // exclusive prefix
  gbase[tid] = h ? atomicAdd(&bcur[tid], h) : 0;
  __syncthreads();
#pragma unroll
  for (int e = 0; e < 16; ++e) {
    if (bb[e] >= 0) {
      int p = lbase[bb[e]] + lp[e];
      stg[p] = ent[e];
      binof[p] = (unsigned char)bb[e];
    }
  }
  __syncthreads();
  for (int i = tid; i < n; i += 256) {
    int b = binof[i];
    int p = gbase[b] + (i - lbase[b]);
    if (p < CAP1B) e1[(size_t)b * CAP1B + p] = stg[i];
  }
}

// ---------------------------------------------------------------------------
// Pass 2 FUSED: per (bucket, chunk): in-LDS sort by local row (32 bins),
// then consume the row-grouped entries directly with register accumulation
// (zero atomics), write [32][16] partials. e2 / tail_zero / accum_csr gone.
__global__ __launch_bounds__(256) void pass2_accum(
    const uint2* __restrict__ e1,
    const int* __restrict__ bcur,
    const float* __restrict__ srcT,     // [8320][16]
    float* __restrict__ partials) {     // [NBK][SB2][32][16]
  int bucket = blockIdx.x / SB2;
  int ch = blockIdx.x - bucket * SB2;
  int tid = threadIdx.x;
  float* __restrict__ pb = partials + ((size_t)bucket * SB2 + ch) * (32 * 16);

  int cnt = bcur[bucket];
  if (cnt > CAP1B) cnt = CAP1B;
  int base = ch * CHUNK;
  if (base >= cnt) {                    // block-uniform: zero partials, exit
    for (int i = tid; i < 32 * 16; i += 256) pb[i] = 0.0f;
    return;
  }
  int n = cnt - base;
  if (n > CHUNK) n = CHUNK;

  __shared__ int hist[32];
  __shared__ int sbase[33];             // exclusive boundaries, sbase[32]=n
  __shared__ uint2 stg[CHUNK];          // 32 KB
  if (tid < 32) hist[tid] = 0;
  __syncthreads();

  const uint2* __restrict__ src = e1 + (size_t)bucket * CAP1B + base;
  uint2 ent[16];
  int rr_[16], lp[16];
#pragma unroll
  for (int e = 0; e < 16; ++e) {
    int i = e * 256 + tid;
    rr_[e] = -1;
    if (i < n) {
      ent[e] = src[i];
      rr_[e] = (int)(ent[e].y >> 14);   // local row 0..31
      lp[e] = atomicAdd(&hist[rr_[e]], 1);
    }
  }
  __syncthreads();
  if (tid < 64) {                       // one wave scans the 32 bins
    int h = (tid < 32) ? hist[tid] : 0;
    int v = h;
#pragma unroll
    for (int d = 1; d < 32; d <<= 1) {
      int t = __shfl_up(v, d);
      if ((tid & 63) >= d) v += t;
    }
    if (tid < 32) sbase[tid] = v - h;
    if (tid == 31) sbase[32] = v;
  }
  __syncthreads();
#pragma unroll
  for (int e = 0; e < 16; ++e)
    if (rr_[e] >= 0) stg[sbase[rr_[e]] + lp[e]] = ent[e];
  __syncthreads();

  // Segmented accumulation: wave w handles rows w*8..w*8+7; the 4 quarters
  // of the wave cooperate on one row at a time, 4 entries/step. Broadcast
  // ds_read within each 16-lane quarter; one 64B srcT line per quarter.
  int wave = tid >> 6, lane = tid & 63;
  int q = lane >> 4, lb = lane & 15;
  for (int rr = wave * 8; rr < wave * 8 + 8; ++rr) {
    int s0 = sbase[rr], s1 = sbase[rr + 1];
    float acc = 0.0f;
    for (int i = s0 + q; i < s1; i += 4) {
      uint2 ee = stg[i];
      float vv = __uint_as_float(ee.x);
      int c = (int)(ee.y & 16383u);
      acc += vv * srcT[c * 16 + lb];
    }
    acc += __shfl_xor(acc, 16);
    acc += __shfl_xor(acc, 32);
    if (lane < 16) pb[rr * 16 + lb] = acc;
  }
}

// ---------------------------------------------------------------------------
__global__ __launch_bounds__(256) void finalize_fused(
    const float* __restrict__ partials,  // [NBK][SB2][32][16]
    const float* __restrict__ state,     // [BATCH][N_RES]
    const float* __restrict__ res_bias,
    const float* __restrict__ in_bias,
    float* __restrict__ out) {           // [BATCH][N_RES]
  int tid = blockIdx.x * 256 + threadIdx.x;
  if (tid >= N_RES * BATCH) return;
  int b = tid >> 13;
  int r = tid & (N_RES - 1);
  int bucket = r >> 5, rr = r & 31;
  const float* __restrict__ p =
      partials + (size_t)bucket * SB2 * 512 + rr * 16 + b;
  float z = 0.0f;
#pragma unroll
  for (int ch = 0; ch < SB2; ++ch) z += p[ch * 512];
  z += res_bias[r] + in_bias[r];
  out[tid] = (1.0f - LEAK) * state[tid] + LEAK * erff(z);
}

// ---------------------------------------------------------------------------
// Fallback (small ws): atomic path, correct but slow.
__global__ __launch_bounds__(256) void spmm_atomic(
    const float* __restrict__ vals,
    const int* __restrict__ rows,
    const int* __restrict__ cols,
    const float* __restrict__ srcT, int col_off,
    float* __restrict__ zz, int nnz) {
  int i = blockIdx.x * blockDim.x + threadIdx.x;
  if (i >= nnz) return;
  float v = vals[i];
  int r = rows[i];
  int c = cols[i] + col_off;
  const float4* __restrict__ sp = (const float4*)(srcT + c * BATCH);
  float* zr = zz + r * BATCH;
#pragma unroll
  for (int qq = 0; qq < 4; ++qq) {
    float4 s = sp[qq];
    unsafeAtomicAdd(zr + qq * 4 + 0, v * s.x);
    unsafeAtomicAdd(zr + qq * 4 + 1, v * s.y);
    unsafeAtomicAdd(zr + qq * 4 + 2, v * s.z);
    unsafeAtomicAdd(zr + qq * 4 + 3, v * s.w);
  }
}

__global__ __launch_bounds__(256) void finalize_z(
    const float* __restrict__ z,        // [N_RES][16]
    const float* __restrict__ state,
    const float* __restrict__ res_bias,
    const float* __restrict__ in_bias,
    float* __restrict__ out) {
  int tid = blockIdx.x * 256 + threadIdx.x;
  if (tid >= BATCH * N_RES) return;
  int b = tid >> 13;
  int r = tid & (N_RES - 1);
  float zz = z[r * 16 + b] + res_bias[r] + in_bias[r];
  out[tid] = (1.0f - LEAK) * state[tid] + LEAK * erff(zz);
}

// ---------------------------------------------------------------------------
extern "C" void kernel_launch(void* const* d_in, const int* in_sizes, int n_in,
                              void* d_out, int out_size, void* d_ws, size_t ws_size,
                              hipStream_t stream) {
  const float* state    = (const float*)d_in[0];
  const float* x        = (const float*)d_in[1];
  const float* res_vals = (const float*)d_in[2];
  const int*   res_rows = (const int*)d_in[3];
  const int*   res_cols = (const int*)d_in[4];
  const float* res_bias = (const float*)d_in[5];
  const float* in_vals  = (const float*)d_in[6];
  const int*   in_rows  = (const int*)d_in[7];
  const int*   in_cols  = (const int*)d_in[8];
  const float* in_bias  = (const float*)d_in[9];

  const int res_nnz = in_sizes[2];
  const int in_nnz  = in_sizes[6];

  char* ws = (char*)d_ws;
  float* srcT = (float*)(ws + OFF_SRCT);
  float* out = (float*)d_out;

  if (ws_size >= REQ_A) {
    int* bcur = (int*)(ws + OFF_BCUR);
    float* partials = (float*)(ws + OFF_PART);
    uint2* e1 = (uint2*)(ws + OFF_E1);

    hipMemsetAsync(bcur, 0, NBK * sizeof(int), stream);
    transpose_kernel<<<512, 256, 0, stream>>>(state, x, srcT);

    pass1_bin<<<(res_nnz + CHUNK - 1) / CHUNK, 256, 0, stream>>>(
        res_vals, res_rows, res_cols, res_nnz, 0, e1, bcur);
    pass1_bin<<<(in_nnz + CHUNK - 1) / CHUNK, 256, 0, stream>>>(
        in_vals, in_rows, in_cols, in_nnz, N_RES, e1, bcur);

    pass2_accum<<<NBK * SB2, 256, 0, stream>>>(e1, bcur, srcT, partials);

    finalize_fused<<<512, 256, 0, stream>>>(
        partials, state, res_bias, in_bias, out);
  } else {
    float* z = (float*)(ws + OFF_PART);
    hipMemsetAsync(z, 0, N_RES * BATCH * sizeof(float), stream);
    transpose_kernel<<<512, 256, 0, stream>>>(state, x, srcT);
    spmm_atomic<<<(res_nnz + 255) / 256, 256, 0, stream>>>(
        res_vals, res_rows, res_cols, srcT, 0, z, res_nnz);
    spmm_atomic<<<(in_nnz + 255) / 256, 256, 0, stream>>>(
        in_vals, in_rows, in_cols, srcT, N_RES, z, in_nnz);
    finalize_z<<<512, 256, 0, stream>>>(z, state, res_bias, in_bias, out);
  }
}